// Round 16
// baseline (1010.230 us; speedup 1.0000x reference)
//
#include <hip/hip_runtime.h>
#include <hip/hip_bf16.h>

typedef unsigned short u16;
typedef unsigned int u32;
typedef __attribute__((ext_vector_type(8))) short bf16x8;
typedef __attribute__((ext_vector_type(4))) float f32x4;
typedef __attribute__((ext_vector_type(4))) float float4v;

__device__ __forceinline__ float bf2f(u16 v) {
  union { u32 u; float f; } x; x.u = ((u32)v) << 16; return x.f;
}
__device__ __forceinline__ u16 f2bf(float f) {
  union { u32 u; float f; } x; x.f = f;
  return (u16)((x.u + 0x7fffu + ((x.u >> 16) & 1u)) >> 16);
}

__device__ __forceinline__ void gload16(const void* g, void* l) {
  __builtin_amdgcn_global_load_lds(
      (const __attribute__((address_space(1))) u32*)g,
      (__attribute__((address_space(3))) u32*)l, 16, 0, 0);
}

#define MFMA16(a, bfr, cacc) __builtin_amdgcn_mfma_f32_16x16x32_bf16((a), (bfr), (cacc), 0, 0, 0)

// ---------------- prep kernels ----------------

__global__ void convert_bf16_kernel(const float* __restrict__ in,
                                    u16* __restrict__ out, int n8) {
  int t = blockIdx.x * blockDim.x + threadIdx.x;
  if (t >= n8) return;
  const float4v* p = (const float4v*)(in + (size_t)t * 8);
  float4v a = p[0], b = p[1];
  union { bf16x8 v; u16 s[8]; } o;
  o.s[0] = f2bf(a[0]); o.s[1] = f2bf(a[1]); o.s[2] = f2bf(a[2]); o.s[3] = f2bf(a[3]);
  o.s[4] = f2bf(b[0]); o.s[5] = f2bf(b[1]); o.s[6] = f2bf(b[2]); o.s[7] = f2bf(b[3]);
  *(bf16x8*)(out + (size_t)t * 8) = o.v;
}

__global__ void transpose_kernel(const float* __restrict__ in, u16* __restrict__ out,
                                 int R, int C) {
  int t = blockIdx.x * blockDim.x + threadIdx.x;
  if (t >= R * C) return;
  int c = t / R, r = t % R;
  out[t] = f2bf(in[r * C + c]);
}

__global__ void bias_tab_kernel(const float* __restrict__ w1, const float* __restrict__ w2,
                                float* __restrict__ tab) {
  int t = blockIdx.x * blockDim.x + threadIdx.x;
  if (t >= 225 * 16) return;
  int r = t >> 4, h = t & 15;
  int i = r / 15, j = r % 15;
  float gi = (float)(i - 7) * (8.0f / 7.0f);
  float gj = (float)(j - 7) * (8.0f / 7.0f);
  float si = (gi > 0.f) ? 1.f : ((gi < 0.f) ? -1.f : 0.f);
  float sj = (gj > 0.f) ? 1.f : ((gj < 0.f) ? -1.f : 0.f);
  float t0 = si * log2f(fabsf(gi) + 1.0f) * (1.0f / 3.0f);
  float t1 = sj * log2f(fabsf(gj) + 1.0f) * (1.0f / 3.0f);
  float acc = 0.f;
  for (int k = 0; k < 512; ++k) {
    float a = t0 * w1[k] + t1 * w1[512 + k];
    float hs = a * fminf(fmaxf(a + 3.f, 0.f), 6.f) * (1.f / 6.f);
    acc += hs * w2[k * 16 + h];
  }
  tab[t] = acc;
}

__global__ void bias16_kernel(const float* __restrict__ tab, float* __restrict__ b16) {
  int t = blockIdx.x * blockDim.x + threadIdx.x;
  if (t >= 16 * 64 * 64) return;
  int h = t >> 12, nm = t & 4095, n = nm >> 6, m = nm & 63;
  int idx = ((n >> 3) - (m >> 3) + 7) * 15 + ((n & 7) - (m & 7) + 7);
  float b = tab[idx * 16 + h];
  b16[t] = 16.0f / (1.0f + expf(-b));
}

// ---------------- 128^2 q/k GEMM + fused cosine-norm + head-major store -----------
// Covers N=1024 (q|k): bn 0-3 q (normalize*scale), 4-7 k (normalize).
// Out: [s*16+h][b][n][d]. Separate kernel from V so regalloc stays lean (84 VGPR).
__global__ __launch_bounds__(256) void gemm_qk(const u16* __restrict__ A,
                                               const u16* __restrict__ Bt,
                                               u16* __restrict__ Cq,
                                               const float* __restrict__ lscale,
                                               int M, int K) {
  __shared__ u16 lds[128 * 136];  // 34,816 B; lA/lB alias front, ct uses all
  u16* lA = lds;
  u16* lB = lds + 8192;
  const int tid = threadIdx.x;
  const int w = tid >> 6, l = tid & 63;
  const int lg = l >> 4, li = l & 15;
  const int nbn = 8;
  const int nwg = gridDim.x;
  int bidx = blockIdx.x;
  int q = nwg >> 3, r = nwg & 7;
  int xcd = bidx & 7, pos = bidx >> 3;
  int swz = (xcd < r ? xcd * (q + 1) : r * (q + 1) + (xcd - r) * q) + pos;
  int bm = swz / nbn, bn = swz % nbn;
  const int wr = w >> 1, wc = w & 1;

  f32x4 acc[4][4];
#pragma unroll
  for (int i = 0; i < 4; i++)
#pragma unroll
    for (int j = 0; j < 4; j++) acc[i][j] = (f32x4){0.f, 0.f, 0.f, 0.f};

  const u16* Abase = A + (size_t)(bm * 128) * K;
  const u16* Bbase = Bt + (size_t)(bn * 128) * K;

  for (int k0 = 0; k0 < K; k0 += 64) {
#pragma unroll
    for (int i = 0; i < 4; ++i) {
      int c = w * 256 + i * 64 + l;
      int row = c >> 3, kc = c & 7;
      int kcs = kc ^ (row & 7);  // source pre-swizzle (rule 21)
      gload16(Abase + (size_t)row * K + k0 + kcs * 8, lA + c * 8);
      gload16(Bbase + (size_t)row * K + k0 + kcs * 8, lB + c * 8);
    }
    __syncthreads();
#pragma unroll
    for (int kk = 0; kk < 2; ++kk) {
      bf16x8 af[4], bfr[4];
#pragma unroll
      for (int t = 0; t < 4; ++t) {
        int row = wr * 64 + t * 16 + li;
        af[t] = *(const bf16x8*)&lA[row * 64 + (((kk * 4 + lg) ^ (row & 7)) << 3)];
        int col = wc * 64 + t * 16 + li;
        bfr[t] = *(const bf16x8*)&lB[col * 64 + (((kk * 4 + lg) ^ (col & 7)) << 3)];
      }
#pragma unroll
      for (int tm = 0; tm < 4; ++tm)
#pragma unroll
        for (int tn = 0; tn < 4; ++tn)
          acc[tm][tn] = MFMA16(af[tm], bfr[tn], acc[tm][tn]);
    }
    __syncthreads();
  }

  const int s_t = bn >> 2;          // 0=q 1=k
  const int hq = (bn & 3) * 4;      // first head of this col-tile
  // ---- normalize rows per head (d=32 within wave half); fold scale into q ----
  float scv[2];
  if (s_t == 0) {
    scv[0] = __expf(fminf(lscale[hq + wc * 2 + 0], 4.6051702f));
    scv[1] = __expf(fminf(lscale[hq + wc * 2 + 1], 4.6051702f));
  } else {
    scv[0] = scv[1] = 1.0f;
  }
#pragma unroll
  for (int tm = 0; tm < 4; ++tm)
#pragma unroll
    for (int g = 0; g < 2; ++g) {
      f32x4 s2;
#pragma unroll
      for (int j = 0; j < 4; ++j)
        s2[j] = acc[tm][2 * g][j] * acc[tm][2 * g][j] +
                acc[tm][2 * g + 1][j] * acc[tm][2 * g + 1][j];
#pragma unroll
      for (int m = 1; m <= 8; m <<= 1)
#pragma unroll
        for (int j = 0; j < 4; ++j) s2[j] += __shfl_xor(s2[j], m);
#pragma unroll
      for (int j = 0; j < 4; ++j) {
        float rn = scv[g] / fmaxf(sqrtf(s2[j]), 1e-12f);
        acc[tm][2 * g][j] *= rn;
        acc[tm][2 * g + 1][j] *= rn;
      }
    }
  // ---- ct bounce [128 rows][136], head-major coalesced store ----
  u16* ct = lds;
#pragma unroll
  for (int tm = 0; tm < 4; ++tm)
#pragma unroll
    for (int tn = 0; tn < 4; ++tn)
#pragma unroll
      for (int j = 0; j < 4; ++j)
        ct[(wr * 64 + tm * 16 + lg * 4 + j) * 136 + wc * 64 + tn * 16 + li] =
            f2bf(acc[tm][tn][j]);
  __syncthreads();
  {
    int rr = tid >> 2;           // 0..63 row within window
    int c8 = (tid & 3) * 8;      // col-in-head offset
#pragma unroll
    for (int bh = 0; bh < 2; ++bh)
#pragma unroll
      for (int ht = 0; ht < 4; ++ht) {
        bf16x8 v = *(const bf16x8*)(ct + (bh * 64 + rr) * 136 + ht * 32 + c8);
        size_t base = ((size_t)(s_t * 16 + hq + ht) * 2048 + (bm * 2 + bh)) * 2048;
        *(bf16x8*)(Cq + base + rr * 32 + c8) = v;
      }
  }
}

// ---------------- 128^2 V GEMM + transposed store [32+h][b][d][n] -----------------
__global__ __launch_bounds__(256) void gemm_v(const u16* __restrict__ A,
                                              const u16* __restrict__ Bt,
                                              u16* __restrict__ Cq,
                                              int M, int K) {
  __shared__ u16 lds[128 * 136];
  u16* lA = lds;
  u16* lB = lds + 8192;
  const int tid = threadIdx.x;
  const int w = tid >> 6, l = tid & 63;
  const int lg = l >> 4, li = l & 15;
  const int nbn = 4;
  const int nwg = gridDim.x;
  int bidx = blockIdx.x;
  int q = nwg >> 3, r = nwg & 7;
  int xcd = bidx & 7, pos = bidx >> 3;
  int swz = (xcd < r ? xcd * (q + 1) : r * (q + 1) + (xcd - r) * q) + pos;
  int bm = swz / nbn, bn = swz % nbn;
  const int wr = w >> 1, wc = w & 1;

  f32x4 acc[4][4];
#pragma unroll
  for (int i = 0; i < 4; i++)
#pragma unroll
    for (int j = 0; j < 4; j++) acc[i][j] = (f32x4){0.f, 0.f, 0.f, 0.f};

  const u16* Abase = A + (size_t)(bm * 128) * K;
  const u16* Bbase = Bt + (size_t)(bn * 128) * K;

  for (int k0 = 0; k0 < K; k0 += 64) {
#pragma unroll
    for (int i = 0; i < 4; ++i) {
      int c = w * 256 + i * 64 + l;
      int row = c >> 3, kc = c & 7;
      int kcs = kc ^ (row & 7);
      gload16(Abase + (size_t)row * K + k0 + kcs * 8, lA + c * 8);
      gload16(Bbase + (size_t)row * K + k0 + kcs * 8, lB + c * 8);
    }
    __syncthreads();
#pragma unroll
    for (int kk = 0; kk < 2; ++kk) {
      bf16x8 af[4], bfr[4];
#pragma unroll
      for (int t = 0; t < 4; ++t) {
        int row = wr * 64 + t * 16 + li;
        af[t] = *(const bf16x8*)&lA[row * 64 + (((kk * 4 + lg) ^ (row & 7)) << 3)];
        int col = wc * 64 + t * 16 + li;
        bfr[t] = *(const bf16x8*)&lB[col * 64 + (((kk * 4 + lg) ^ (col & 7)) << 3)];
      }
#pragma unroll
      for (int tm = 0; tm < 4; ++tm)
#pragma unroll
        for (int tn = 0; tn < 4; ++tn)
          acc[tm][tn] = MFMA16(af[tm], bfr[tn], acc[tm][tn]);
    }
    __syncthreads();
  }

  const int hq = bn * 4;
  // ---- transposed bounce ctT[128 cols][136 rows], store [32+h][b][d][n] ----
  u16* ctT = lds;
#pragma unroll
  for (int tm = 0; tm < 4; ++tm)
#pragma unroll
    for (int tn = 0; tn < 4; ++tn)
#pragma unroll
      for (int j = 0; j < 4; ++j)
        ctT[(wc * 64 + tn * 16 + li) * 136 + wr * 64 + tm * 16 + lg * 4 + j] =
            f2bf(acc[tm][tn][j]);
  __syncthreads();
#pragma unroll
  for (int r2 = 0; r2 < 8; ++r2) {
    int id = r2 * 256 + tid;
    int colc = id >> 4;          // 0..127 -> (ht, d)
    int seg = id & 15;           // 8-row segment -> (wi, n0)
    bf16x8 v = *(const bf16x8*)&ctT[colc * 136 + seg * 8];
    int ht = colc >> 5, d = colc & 31;
    int wi = seg >> 3, n0 = (seg & 7) * 8;
    size_t base = ((size_t)(32 + hq + ht) * 2048 + (bm * 2 + wi)) * 2048;
    *(bf16x8*)(Cq + base + d * 64 + n0) = v;
  }
}

// ---------------- attention + fused out-projection ---------------------------------
// q,k head-major [h][b][n][d]; V^T [h][b][d][n]. After PV: o16 bf16 LDS tile
// [64][522] (522-pad: 16-distinct-bank stride) -> per-wave 64x64 out-proj tile in
// two 32-col passes (acc 32 VGPR), B-frags from L2-hot woutT, fp32 stores to d_out.
__global__ __launch_bounds__(512, 2) void attn2(const u16* __restrict__ qkv,
                                                const float* __restrict__ mask,
                                                const float* __restrict__ bias16,
                                                const u16* __restrict__ woT,
                                                float* __restrict__ outp) {
  __shared__ float S[16704];         // 66,816 B; [h][m][65n] softmax / o16 [64][522]
  u16* P16 = (u16*)S;
  u16* o16 = (u16*)S;
  const int tid = threadIdx.x;
  const int w = tid >> 6, l = tid & 63;
  const int lg = l >> 4, li = l & 15;
  const int b = blockIdx.x, wm = b & 63;
  const float* mask_w = mask + wm * 4096;

  // hoist Q fragments (loaded once, used in all 4 chunks)
  bf16x8 qfr[2][4];
#pragma unroll
  for (int hp = 0; hp < 2; ++hp) {
    const u16* qb = qkv + ((size_t)(w + hp * 8) * 2048 + b) * 2048;
#pragma unroll
    for (int tn = 0; tn < 4; ++tn)
      qfr[hp][tn] = *(const bf16x8*)(qb + (tn * 16 + li) * 32 + lg * 8);
  }

  f32x4 oacc[2][4][2];
#pragma unroll
  for (int hp = 0; hp < 2; ++hp)
#pragma unroll
    for (int i = 0; i < 4; ++i) {
      oacc[hp][i][0] = (f32x4){0.f, 0.f, 0.f, 0.f};
      oacc[hp][i][1] = (f32x4){0.f, 0.f, 0.f, 0.f};
    }

#pragma unroll
  for (int c = 0; c < 4; ++c) {
    // ---- QK^T chunk (16 keys) + bias + mask -> S ----
#pragma unroll
    for (int hp = 0; hp < 2; ++hp) {
      int h = w + hp * 8;
      const u16* kb = qkv + ((size_t)(16 + h) * 2048 + b) * 2048;
      const float* bias_h = bias16 + h * 4096;
      bf16x8 kfc = *(const bf16x8*)(kb + (c * 16 + li) * 32 + lg * 8);
      int mg = c * 16 + li;
#pragma unroll
      for (int tn = 0; tn < 4; ++tn) {
        f32x4 z = {0.f, 0.f, 0.f, 0.f};
        f32x4 s = MFMA16(qfr[hp][tn], kfc, z);
#pragma unroll
        for (int j = 0; j < 4; ++j) {
          int n = tn * 16 + lg * 4 + j;
          S[h * 1040 + li * 65 + n] = s[j] + bias_h[n * 64 + mg] + mask_w[n * 64 + mg];
        }
      }
    }
    __syncthreads();
    // ---- softmax over 16 heads per (m,n): single read pass, vals in regs ----
#pragma unroll
    for (int pp = 0; pp < 2; ++pp) {
      int p = tid + pp * 512;
      int base = (p >> 6) * 65 + (p & 63);
      float vals[16];
      float mx = -3.0e38f;
#pragma unroll
      for (int hh = 0; hh < 16; ++hh) {
        vals[hh] = S[hh * 1040 + base];
        mx = fmaxf(mx, vals[hh]);
      }
      float sum = 0.f;
#pragma unroll
      for (int hh = 0; hh < 16; ++hh) {
        float e = __expf(vals[hh] - mx);
        vals[hh] = e;
        sum += e;
      }
      float inv = 1.0f / sum;
#pragma unroll
      for (int hh = 0; hh < 16; ++hh)
        P16[(hh * 1040 + base) * 2] = f2bf(vals[hh] * inv);
    }
    __syncthreads();
    // ---- PV (K=32 MFMA, upper 16 keys zero); V^T vector loads ----
#pragma unroll
    for (int hp = 0; hp < 2; ++hp) {
      int h = w + hp * 8;
      const u16* vbT = qkv + ((size_t)(32 + h) * 2048 + b) * 2048;
      bf16x8 vf[2];
      if (lg < 2) {
#pragma unroll
        for (int td = 0; td < 2; ++td)
          vf[td] = *(const bf16x8*)(vbT + (td * 16 + li) * 64 + c * 16 + lg * 8);
      } else {
#pragma unroll
        for (int td = 0; td < 2; ++td)
#pragma unroll
          for (int e = 0; e < 8; ++e) vf[td][e] = 0;
      }
#pragma unroll
      for (int tn = 0; tn < 4; ++tn) {
        bf16x8 pf;
#pragma unroll
        for (int e = 0; e < 8; ++e)
          pf[e] = (lg < 2)
                      ? (short)P16[(h * 1040 + (lg * 8 + e) * 65 + tn * 16 + li) * 2]
                      : (short)0;
        oacc[hp][tn][0] = MFMA16(pf, vf[0], oacc[hp][tn][0]);
        oacc[hp][tn][1] = MFMA16(pf, vf[1], oacc[hp][tn][1]);
      }
    }
    __syncthreads();
  }

  // ---- fused out-projection: oacc -> o16 bf16 LDS [64][522] ----
#pragma unroll
  for (int tn = 0; tn < 4; ++tn)
#pragma unroll
    for (int hp = 0; hp < 2; ++hp)
#pragma unroll
      for (int td = 0; td < 2; ++td)
#pragma unroll
        for (int j = 0; j < 4; ++j)
          o16[(tn * 16 + lg * 4 + j) * 522 + (w + hp * 8) * 32 + td * 16 + li] =
              f2bf(oacc[hp][tn][td][j]);
  __syncthreads();
  // per-wave 64x64 tile of out = o @ w_out, two 32-col passes
#pragma unroll
  for (int p = 0; p < 2; ++p) {
    f32x4 acc2[4][2];
#pragma unroll
    for (int i = 0; i < 4; ++i) {
      acc2[i][0] = (f32x4){0.f, 0.f, 0.f, 0.f};
      acc2[i][1] = (f32x4){0.f, 0.f, 0.f, 0.f};
    }
#pragma unroll
    for (int kk = 0; kk < 16; ++kk) {
      bf16x8 af[4];
#pragma unroll
      for (int t = 0; t < 4; ++t)
        af[t] = *(const bf16x8*)&o16[(t * 16 + li) * 522 + kk * 32 + lg * 8];
      bf16x8 bf2[2];
#pragma unroll
      for (int tn = 0; tn < 2; ++tn)
        bf2[tn] = *(const bf16x8*)(woT +
                                   (size_t)(w * 64 + p * 32 + tn * 16 + li) * 512 +
                                   kk * 32 + lg * 8);
#pragma unroll
      for (int tm = 0; tm < 4; ++tm)
#pragma unroll
        for (int tn = 0; tn < 2; ++tn)
          acc2[tm][tn] = MFMA16(af[tm], bf2[tn], acc2[tm][tn]);
    }
#pragma unroll
    for (int tm = 0; tm < 4; ++tm)
#pragma unroll
      for (int tn = 0; tn < 2; ++tn)
#pragma unroll
        for (int j = 0; j < 4; ++j)
          outp[((size_t)b * 64 + tm * 16 + lg * 4 + j) * 512 +
               w * 64 + p * 32 + tn * 16 + li] = acc2[tm][tn][j];
  }
}

extern "C" void kernel_launch(void* const* d_in, const int* in_sizes, int n_in,
                              void* d_out, int out_size, void* d_ws, size_t ws_size,
                              hipStream_t stream) {
  const float* x = (const float*)d_in[0];
  const float* mask = (const float*)d_in[1];
  const float* w_qkv = (const float*)d_in[2];
  const float* w_out = (const float*)d_in[3];
  const float* cpb_w1 = (const float*)d_in[4];
  const float* cpb_w2 = (const float*)d_in[5];
  const float* lscale = (const float*)d_in[6];
  float* out = (float*)d_out;

  char* ws = (char*)d_ws;
  u16* wqkvT = (u16*)ws;                         // 1,572,864 B
  u16* woutT = (u16*)(ws + 1572864ull);          // 524,288 B
  float* btab = (float*)(ws + 2097152ull);       // 16,384 B
  float* b16 = (float*)(ws + 2113536ull);        // 262,144 B
  u16* qkv_ws = (u16*)(ws + 2375680ull);         // 402,653,184 B (head-major / V^T)
  u16* xb = (u16*)(ws + 2375680ull + 402653184ull);  // 134,217,728 B

  // prep
  transpose_kernel<<<(512 * 1536 + 255) / 256, 256, 0, stream>>>(w_qkv, wqkvT, 512, 1536);
  transpose_kernel<<<(512 * 512 + 255) / 256, 256, 0, stream>>>(w_out, woutT, 512, 512);
  bias_tab_kernel<<<(225 * 16 + 255) / 256, 256, 0, stream>>>(cpb_w1, cpb_w2, btab);
  bias16_kernel<<<(16 * 64 * 64 + 255) / 256, 256, 0, stream>>>(btab, b16);

  // x -> bf16
  convert_bf16_kernel<<<(131072 * 64 + 255) / 256, 256, 0, stream>>>(x, xb, 131072 * 64);

  // q/k GEMM (fused norm/scale, head-major) and V GEMM (transposed) — split kernels
  gemm_qk<<<8192, 256, 0, stream>>>(xb, wqkvT, qkv_ws, lscale, 131072, 512);
  gemm_v<<<4096, 256, 0, stream>>>(xb, wqkvT + (size_t)1024 * 512, qkv_ws, 131072, 512);

  // attention + fused out-projection (writes fp32 d_out directly)
  attn2<<<2048, 512, 0, stream>>>(qkv_ws, mask, b16, woutT, out);
}

// Round 17
// 906.931 us; speedup vs baseline: 1.1139x; 1.1139x over previous
//
#include <hip/hip_runtime.h>
#include <hip/hip_bf16.h>

typedef unsigned short u16;
typedef unsigned int u32;
typedef __attribute__((ext_vector_type(8))) short bf16x8;
typedef __attribute__((ext_vector_type(4))) float f32x4;
typedef __attribute__((ext_vector_type(4))) float float4v;

__device__ __forceinline__ float bf2f(u16 v) {
  union { u32 u; float f; } x; x.u = ((u32)v) << 16; return x.f;
}
__device__ __forceinline__ u16 f2bf(float f) {
  union { u32 u; float f; } x; x.f = f;
  return (u16)((x.u + 0x7fffu + ((x.u >> 16) & 1u)) >> 16);
}

__device__ __forceinline__ void gload16(const void* g, void* l) {
  __builtin_amdgcn_global_load_lds(
      (const __attribute__((address_space(1))) u32*)g,
      (__attribute__((address_space(3))) u32*)l, 16, 0, 0);
}

#define MFMA16(a, bfr, cacc) __builtin_amdgcn_mfma_f32_16x16x32_bf16((a), (bfr), (cacc), 0, 0, 0)

// ---------------- prep kernels ----------------

__global__ void convert_bf16_kernel(const float* __restrict__ in,
                                    u16* __restrict__ out, int n8) {
  int t = blockIdx.x * blockDim.x + threadIdx.x;
  if (t >= n8) return;
  const float4v* p = (const float4v*)(in + (size_t)t * 8);
  float4v a = p[0], b = p[1];
  union { bf16x8 v; u16 s[8]; } o;
  o.s[0] = f2bf(a[0]); o.s[1] = f2bf(a[1]); o.s[2] = f2bf(a[2]); o.s[3] = f2bf(a[3]);
  o.s[4] = f2bf(b[0]); o.s[5] = f2bf(b[1]); o.s[6] = f2bf(b[2]); o.s[7] = f2bf(b[3]);
  *(bf16x8*)(out + (size_t)t * 8) = o.v;
}

__global__ void transpose_kernel(const float* __restrict__ in, u16* __restrict__ out,
                                 int R, int C) {
  int t = blockIdx.x * blockDim.x + threadIdx.x;
  if (t >= R * C) return;
  int c = t / R, r = t % R;
  out[t] = f2bf(in[r * C + c]);
}

// maskT[wm][m][n] = mask[wm][n][m]  (fp32, coalesced writes)
__global__ void mask_t_kernel(const float* __restrict__ in, float* __restrict__ out) {
  int t = blockIdx.x * blockDim.x + threadIdx.x;
  if (t >= 64 * 4096) return;
  int wm = t >> 12, rest = t & 4095, m = rest >> 6, n = rest & 63;
  out[t] = in[wm * 4096 + n * 64 + m];
}

__global__ void bias_tab_kernel(const float* __restrict__ w1, const float* __restrict__ w2,
                                float* __restrict__ tab) {
  int t = blockIdx.x * blockDim.x + threadIdx.x;
  if (t >= 225 * 16) return;
  int r = t >> 4, h = t & 15;
  int i = r / 15, j = r % 15;
  float gi = (float)(i - 7) * (8.0f / 7.0f);
  float gj = (float)(j - 7) * (8.0f / 7.0f);
  float si = (gi > 0.f) ? 1.f : ((gi < 0.f) ? -1.f : 0.f);
  float sj = (gj > 0.f) ? 1.f : ((gj < 0.f) ? -1.f : 0.f);
  float t0 = si * log2f(fabsf(gi) + 1.0f) * (1.0f / 3.0f);
  float t1 = sj * log2f(fabsf(gj) + 1.0f) * (1.0f / 3.0f);
  float acc = 0.f;
  for (int k = 0; k < 512; ++k) {
    float a = t0 * w1[k] + t1 * w1[512 + k];
    float hs = a * fminf(fmaxf(a + 3.f, 0.f), 6.f) * (1.f / 6.f);
    acc += hs * w2[k * 16 + h];
  }
  tab[t] = acc;
}

// bias16T[h][m][n] = 16*sigmoid(tab[idx(n,m)][h])   (TRANSPOSED for vector loads)
__global__ void bias16_kernel(const float* __restrict__ tab, float* __restrict__ b16) {
  int t = blockIdx.x * blockDim.x + threadIdx.x;
  if (t >= 16 * 64 * 64) return;
  int h = t >> 12, nm = t & 4095, m = nm >> 6, n = nm & 63;
  int idx = ((n >> 3) - (m >> 3) + 7) * 15 + ((n & 7) - (m & 7) + 7);
  float b = tab[idx * 16 + h];
  b16[t] = 16.0f / (1.0f + expf(-b));
}

// ---------------- m97-style bf16 GEMM (generic, swizzled): out-projection ----------
template <bool F32OUT>
__global__ __launch_bounds__(256) void gemm_bt(const u16* __restrict__ A,
                                               const u16* __restrict__ Bt,
                                               void* __restrict__ Cout,
                                               int M, int N, int K) {
  __shared__ u16 lA[128 * 64];
  __shared__ u16 lB[128 * 64];
  const int tid = threadIdx.x;
  const int w = tid >> 6, l = tid & 63;
  const int lg = l >> 4, li = l & 15;
  const int nbn = N >> 7;
  const int nwg = gridDim.x;
  int bidx = blockIdx.x;
  int q = nwg >> 3, r = nwg & 7;
  int xcd = bidx & 7, pos = bidx >> 3;
  int swz = (xcd < r ? xcd * (q + 1) : r * (q + 1) + (xcd - r) * q) + pos;
  int bm = swz / nbn, bn = swz % nbn;
  const int wr = w >> 1, wc = w & 1;

  f32x4 acc[4][4];
#pragma unroll
  for (int i = 0; i < 4; i++)
#pragma unroll
    for (int j = 0; j < 4; j++) acc[i][j] = (f32x4){0.f, 0.f, 0.f, 0.f};

  const u16* Abase = A + (size_t)(bm * 128) * K;
  const u16* Bbase = Bt + (size_t)(bn * 128) * K;

  for (int k0 = 0; k0 < K; k0 += 64) {
#pragma unroll
    for (int i = 0; i < 4; ++i) {
      int c = w * 256 + i * 64 + l;
      int row = c >> 3, kc = c & 7;
      int kcs = kc ^ (row & 7);
      gload16(Abase + (size_t)row * K + k0 + kcs * 8, (u16*)lA + c * 8);
      gload16(Bbase + (size_t)row * K + k0 + kcs * 8, (u16*)lB + c * 8);
    }
    __syncthreads();
#pragma unroll
    for (int kk = 0; kk < 2; ++kk) {
      bf16x8 af[4], bfr[4];
#pragma unroll
      for (int t = 0; t < 4; ++t) {
        int row = wr * 64 + t * 16 + li;
        af[t] = *(const bf16x8*)&lA[row * 64 + (((kk * 4 + lg) ^ (row & 7)) << 3)];
        int col = wc * 64 + t * 16 + li;
        bfr[t] = *(const bf16x8*)&lB[col * 64 + (((kk * 4 + lg) ^ (col & 7)) << 3)];
      }
#pragma unroll
      for (int tm = 0; tm < 4; ++tm)
#pragma unroll
        for (int tn = 0; tn < 4; ++tn)
          acc[tm][tn] = MFMA16(af[tm], bfr[tn], acc[tm][tn]);
    }
    __syncthreads();
  }
  int r0 = bm * 128 + wr * 64 + lg * 4;
  int c0 = bn * 128 + wc * 64 + li;
#pragma unroll
  for (int tm = 0; tm < 4; ++tm)
#pragma unroll
    for (int tn = 0; tn < 4; ++tn)
#pragma unroll
      for (int j = 0; j < 4; ++j) {
        size_t off = (size_t)(r0 + tm * 16 + j) * N + c0 + tn * 16;
        if (F32OUT)
          ((float*)Cout)[off] = acc[tm][tn][j];
        else
          ((u16*)Cout)[off] = f2bf(acc[tm][tn][j]);
      }
}

// ---------------- 128^2 q/k GEMM + fused cosine-norm + head-major store -----------
__global__ __launch_bounds__(256) void gemm_qk(const u16* __restrict__ A,
                                               const u16* __restrict__ Bt,
                                               u16* __restrict__ Cq,
                                               const float* __restrict__ lscale,
                                               int M, int K) {
  __shared__ u16 lds[128 * 136];
  u16* lA = lds;
  u16* lB = lds + 8192;
  const int tid = threadIdx.x;
  const int w = tid >> 6, l = tid & 63;
  const int lg = l >> 4, li = l & 15;
  const int nbn = 8;
  const int nwg = gridDim.x;
  int bidx = blockIdx.x;
  int q = nwg >> 3, r = nwg & 7;
  int xcd = bidx & 7, pos = bidx >> 3;
  int swz = (xcd < r ? xcd * (q + 1) : r * (q + 1) + (xcd - r) * q) + pos;
  int bm = swz / nbn, bn = swz % nbn;
  const int wr = w >> 1, wc = w & 1;

  f32x4 acc[4][4];
#pragma unroll
  for (int i = 0; i < 4; i++)
#pragma unroll
    for (int j = 0; j < 4; j++) acc[i][j] = (f32x4){0.f, 0.f, 0.f, 0.f};

  const u16* Abase = A + (size_t)(bm * 128) * K;
  const u16* Bbase = Bt + (size_t)(bn * 128) * K;

  for (int k0 = 0; k0 < K; k0 += 64) {
#pragma unroll
    for (int i = 0; i < 4; ++i) {
      int c = w * 256 + i * 64 + l;
      int row = c >> 3, kc = c & 7;
      int kcs = kc ^ (row & 7);  // source pre-swizzle (rule 21)
      gload16(Abase + (size_t)row * K + k0 + kcs * 8, lA + c * 8);
      gload16(Bbase + (size_t)row * K + k0 + kcs * 8, lB + c * 8);
    }
    __syncthreads();
#pragma unroll
    for (int kk = 0; kk < 2; ++kk) {
      bf16x8 af[4], bfr[4];
#pragma unroll
      for (int t = 0; t < 4; ++t) {
        int row = wr * 64 + t * 16 + li;
        af[t] = *(const bf16x8*)&lA[row * 64 + (((kk * 4 + lg) ^ (row & 7)) << 3)];
        int col = wc * 64 + t * 16 + li;
        bfr[t] = *(const bf16x8*)&lB[col * 64 + (((kk * 4 + lg) ^ (col & 7)) << 3)];
      }
#pragma unroll
      for (int tm = 0; tm < 4; ++tm)
#pragma unroll
        for (int tn = 0; tn < 4; ++tn)
          acc[tm][tn] = MFMA16(af[tm], bfr[tn], acc[tm][tn]);
    }
    __syncthreads();
  }

  const int s_t = bn >> 2;          // 0=q 1=k
  const int hq = (bn & 3) * 4;
  float scv[2];
  if (s_t == 0) {
    scv[0] = __expf(fminf(lscale[hq + wc * 2 + 0], 4.6051702f));
    scv[1] = __expf(fminf(lscale[hq + wc * 2 + 1], 4.6051702f));
  } else {
    scv[0] = scv[1] = 1.0f;
  }
#pragma unroll
  for (int tm = 0; tm < 4; ++tm)
#pragma unroll
    for (int g = 0; g < 2; ++g) {
      f32x4 s2;
#pragma unroll
      for (int j = 0; j < 4; ++j)
        s2[j] = acc[tm][2 * g][j] * acc[tm][2 * g][j] +
                acc[tm][2 * g + 1][j] * acc[tm][2 * g + 1][j];
#pragma unroll
      for (int m = 1; m <= 8; m <<= 1)
#pragma unroll
        for (int j = 0; j < 4; ++j) s2[j] += __shfl_xor(s2[j], m);
#pragma unroll
      for (int j = 0; j < 4; ++j) {
        float rn = scv[g] / fmaxf(sqrtf(s2[j]), 1e-12f);
        acc[tm][2 * g][j] *= rn;
        acc[tm][2 * g + 1][j] *= rn;
      }
    }
  u16* ct = lds;
#pragma unroll
  for (int tm = 0; tm < 4; ++tm)
#pragma unroll
    for (int tn = 0; tn < 4; ++tn)
#pragma unroll
      for (int j = 0; j < 4; ++j)
        ct[(wr * 64 + tm * 16 + lg * 4 + j) * 136 + wc * 64 + tn * 16 + li] =
            f2bf(acc[tm][tn][j]);
  __syncthreads();
  {
    int rr = tid >> 2;
    int c8 = (tid & 3) * 8;
#pragma unroll
    for (int bh = 0; bh < 2; ++bh)
#pragma unroll
      for (int ht = 0; ht < 4; ++ht) {
        bf16x8 v = *(const bf16x8*)(ct + (bh * 64 + rr) * 136 + ht * 32 + c8);
        size_t base = ((size_t)(s_t * 16 + hq + ht) * 2048 + (bm * 2 + bh)) * 2048;
        *(bf16x8*)(Cq + base + rr * 32 + c8) = v;
      }
  }
}

// ---------------- 128^2 V GEMM + transposed store [32+h][b][d][n] -----------------
__global__ __launch_bounds__(256) void gemm_v(const u16* __restrict__ A,
                                              const u16* __restrict__ Bt,
                                              u16* __restrict__ Cq,
                                              int M, int K) {
  __shared__ u16 lds[128 * 136];
  u16* lA = lds;
  u16* lB = lds + 8192;
  const int tid = threadIdx.x;
  const int w = tid >> 6, l = tid & 63;
  const int lg = l >> 4, li = l & 15;
  const int nbn = 4;
  const int nwg = gridDim.x;
  int bidx = blockIdx.x;
  int q = nwg >> 3, r = nwg & 7;
  int xcd = bidx & 7, pos = bidx >> 3;
  int swz = (xcd < r ? xcd * (q + 1) : r * (q + 1) + (xcd - r) * q) + pos;
  int bm = swz / nbn, bn = swz % nbn;
  const int wr = w >> 1, wc = w & 1;

  f32x4 acc[4][4];
#pragma unroll
  for (int i = 0; i < 4; i++)
#pragma unroll
    for (int j = 0; j < 4; j++) acc[i][j] = (f32x4){0.f, 0.f, 0.f, 0.f};

  const u16* Abase = A + (size_t)(bm * 128) * K;
  const u16* Bbase = Bt + (size_t)(bn * 128) * K;

  for (int k0 = 0; k0 < K; k0 += 64) {
#pragma unroll
    for (int i = 0; i < 4; ++i) {
      int c = w * 256 + i * 64 + l;
      int row = c >> 3, kc = c & 7;
      int kcs = kc ^ (row & 7);
      gload16(Abase + (size_t)row * K + k0 + kcs * 8, lA + c * 8);
      gload16(Bbase + (size_t)row * K + k0 + kcs * 8, lB + c * 8);
    }
    __syncthreads();
#pragma unroll
    for (int kk = 0; kk < 2; ++kk) {
      bf16x8 af[4], bfr[4];
#pragma unroll
      for (int t = 0; t < 4; ++t) {
        int row = wr * 64 + t * 16 + li;
        af[t] = *(const bf16x8*)&lA[row * 64 + (((kk * 4 + lg) ^ (row & 7)) << 3)];
        int col = wc * 64 + t * 16 + li;
        bfr[t] = *(const bf16x8*)&lB[col * 64 + (((kk * 4 + lg) ^ (col & 7)) << 3)];
      }
#pragma unroll
      for (int tm = 0; tm < 4; ++tm)
#pragma unroll
        for (int tn = 0; tn < 4; ++tn)
          acc[tm][tn] = MFMA16(af[tm], bfr[tn], acc[tm][tn]);
    }
    __syncthreads();
  }

  const int hq = bn * 4;
  u16* ctT = lds;
#pragma unroll
  for (int tm = 0; tm < 4; ++tm)
#pragma unroll
    for (int tn = 0; tn < 4; ++tn)
#pragma unroll
      for (int j = 0; j < 4; ++j)
        ctT[(wc * 64 + tn * 16 + li) * 136 + wr * 64 + tm * 16 + lg * 4 + j] =
            f2bf(acc[tm][tn][j]);
  __syncthreads();
#pragma unroll
  for (int r2 = 0; r2 < 8; ++r2) {
    int id = r2 * 256 + tid;
    int colc = id >> 4;
    int seg = id & 15;
    bf16x8 v = *(const bf16x8*)&ctT[colc * 136 + seg * 8];
    int ht = colc >> 5, d = colc & 31;
    int wi = seg >> 3, n0 = (seg & 7) * 8;
    size_t base = ((size_t)(32 + hq + ht) * 2048 + (bm * 2 + wi)) * 2048;
    *(bf16x8*)(Cq + base + d * 64 + n0) = v;
  }
}

// ---------------- attention-only: q,k head-major [h][b][n][d]; V^T [h][b][d][n] ----
// bias16T [h][m][n] and maskT [w][m][n] enable float4 loads + aligned b128 S writes.
// S row pad = 68 (16B-aligned rows, 2-way banks = free).
__global__ __launch_bounds__(512, 2) void attn2(const u16* __restrict__ qkv,
                                                const float* __restrict__ maskT,
                                                const float* __restrict__ bias16T,
                                                u16* __restrict__ aout) {
  __shared__ float S[16 * 1088];     // [h][m(16)][68-pad n] = 69,632 B
  u16* P16 = (u16*)S;
  float* ob = S;                     // epilogue alias [16][516]
  const int tid = threadIdx.x;
  const int w = tid >> 6, l = tid & 63;
  const int lg = l >> 4, li = l & 15;
  const int b = blockIdx.x, wm = b & 63;
  const float* maskT_w = maskT + wm * 4096;

  // hoist Q fragments (loaded once, used in all 4 chunks)
  bf16x8 qfr[2][4];
#pragma unroll
  for (int hp = 0; hp < 2; ++hp) {
    const u16* qb = qkv + ((size_t)(w + hp * 8) * 2048 + b) * 2048;
#pragma unroll
    for (int tn = 0; tn < 4; ++tn)
      qfr[hp][tn] = *(const bf16x8*)(qb + (tn * 16 + li) * 32 + lg * 8);
  }

  f32x4 oacc[2][4][2];
#pragma unroll
  for (int hp = 0; hp < 2; ++hp)
#pragma unroll
    for (int i = 0; i < 4; ++i) {
      oacc[hp][i][0] = (f32x4){0.f, 0.f, 0.f, 0.f};
      oacc[hp][i][1] = (f32x4){0.f, 0.f, 0.f, 0.f};
    }

#pragma unroll
  for (int c = 0; c < 4; ++c) {
    // ---- QK^T chunk (16 keys) + bias + mask -> S (vector loads + b128 writes) ----
#pragma unroll
    for (int hp = 0; hp < 2; ++hp) {
      int h = w + hp * 8;
      const u16* kb = qkv + ((size_t)(16 + h) * 2048 + b) * 2048;
      const float* biasT_h = bias16T + h * 4096;
      bf16x8 kfc = *(const bf16x8*)(kb + (c * 16 + li) * 32 + lg * 8);
      int mg = c * 16 + li;
#pragma unroll
      for (int tn = 0; tn < 4; ++tn) {
        f32x4 z = {0.f, 0.f, 0.f, 0.f};
        f32x4 s = MFMA16(qfr[hp][tn], kfc, z);
        float4v b4 = *(const float4v*)(biasT_h + mg * 64 + tn * 16 + lg * 4);
        float4v m4 = *(const float4v*)(maskT_w + mg * 64 + tn * 16 + lg * 4);
        *(float4v*)&S[h * 1088 + li * 68 + tn * 16 + lg * 4] = s + b4 + m4;
      }
    }
    __syncthreads();
    // ---- softmax over 16 heads per (m,n): single read pass, vals in regs ----
#pragma unroll
    for (int pp = 0; pp < 2; ++pp) {
      int p = tid + pp * 512;
      int base = (p >> 6) * 68 + (p & 63);
      float vals[16];
      float mx = -3.0e38f;
#pragma unroll
      for (int hh = 0; hh < 16; ++hh) {
        vals[hh] = S[hh * 1088 + base];
        mx = fmaxf(mx, vals[hh]);
      }
      float sum = 0.f;
#pragma unroll
      for (int hh = 0; hh < 16; ++hh) {
        float e = __expf(vals[hh] - mx);
        vals[hh] = e;
        sum += e;
      }
      float inv = 1.0f / sum;
#pragma unroll
      for (int hh = 0; hh < 16; ++hh)
        P16[(hh * 1088 + base) * 2] = f2bf(vals[hh] * inv);
    }
    __syncthreads();
    // ---- PV (K=32 MFMA, upper 16 keys zero); V^T vector loads ----
#pragma unroll
    for (int hp = 0; hp < 2; ++hp) {
      int h = w + hp * 8;
      const u16* vbT = qkv + ((size_t)(32 + h) * 2048 + b) * 2048;
      bf16x8 vf[2];
      if (lg < 2) {
#pragma unroll
        for (int td = 0; td < 2; ++td)
          vf[td] = *(const bf16x8*)(vbT + (td * 16 + li) * 64 + c * 16 + lg * 8);
      } else {
#pragma unroll
        for (int td = 0; td < 2; ++td)
#pragma unroll
          for (int e = 0; e < 8; ++e) vf[td][e] = 0;
      }
#pragma unroll
      for (int tn = 0; tn < 4; ++tn) {
        bf16x8 pf;
#pragma unroll
        for (int e = 0; e < 8; ++e)
          pf[e] = (lg < 2)
                      ? (short)P16[(h * 1088 + (lg * 8 + e) * 68 + tn * 16 + li) * 2]
                      : (short)0;
        oacc[hp][tn][0] = MFMA16(pf, vf[0], oacc[hp][tn][0]);
        oacc[hp][tn][1] = MFMA16(pf, vf[1], oacc[hp][tn][1]);
      }
    }
    __syncthreads();
  }

  // ---- epilogue: 4 row-passes through ob, coalesced stores ----
#pragma unroll
  for (int tn = 0; tn < 4; ++tn) {
#pragma unroll
    for (int hp = 0; hp < 2; ++hp) {
      int h = w + hp * 8;
#pragma unroll
      for (int td = 0; td < 2; ++td)
#pragma unroll
        for (int j = 0; j < 4; ++j)
          ob[(lg * 4 + j) * 516 + h * 32 + td * 16 + li] = oacc[hp][tn][td][j];
    }
    __syncthreads();
    {
      int rr = tid >> 5, c16 = (tid & 31) * 16;
      const float* src = ob + rr * 516 + c16;
      u16* dst = aout + ((size_t)b * 64 + tn * 16 + rr) * 512 + c16;
#pragma unroll
      for (int half = 0; half < 2; ++half) {
        union { bf16x8 v; u16 u[8]; } o;
#pragma unroll
        for (int e = 0; e < 8; ++e) o.u[e] = f2bf(src[half * 8 + e]);
        *(bf16x8*)(dst + half * 8) = o.v;
      }
    }
    __syncthreads();
  }
}

extern "C" void kernel_launch(void* const* d_in, const int* in_sizes, int n_in,
                              void* d_out, int out_size, void* d_ws, size_t ws_size,
                              hipStream_t stream) {
  const float* x = (const float*)d_in[0];
  const float* mask = (const float*)d_in[1];
  const float* w_qkv = (const float*)d_in[2];
  const float* w_out = (const float*)d_in[3];
  const float* cpb_w1 = (const float*)d_in[4];
  const float* cpb_w2 = (const float*)d_in[5];
  const float* lscale = (const float*)d_in[6];
  float* out = (float*)d_out;

  char* ws = (char*)d_ws;
  u16* wqkvT = (u16*)ws;                          // 1,572,864 B
  u16* woutT = (u16*)(ws + 1572864ull);           // 524,288 B
  float* btab = (float*)(ws + 2097152ull);        // 16,384 B
  float* b16 = (float*)(ws + 2113536ull);         // 262,144 B (transposed [h][m][n])
  float* maskT = (float*)(ws + 2375680ull);       // 16,777,216 B ([w][m][n])
  u16* qkv_ws = (u16*)(ws + 19152896ull);         // 402,653,184 B (head-major / V^T)
  u16* xb = (u16*)(ws + 19152896ull + 402653184ull);  // 134,217,728 B
  u16* attn_out = xb;  // alias: xb dead after gemm_qk/gemm_v; attn2 runs after

  // prep
  transpose_kernel<<<(512 * 1536 + 255) / 256, 256, 0, stream>>>(w_qkv, wqkvT, 512, 1536);
  transpose_kernel<<<(512 * 512 + 255) / 256, 256, 0, stream>>>(w_out, woutT, 512, 512);
  bias_tab_kernel<<<(225 * 16 + 255) / 256, 256, 0, stream>>>(cpb_w1, cpb_w2, btab);
  bias16_kernel<<<(16 * 64 * 64 + 255) / 256, 256, 0, stream>>>(btab, b16);
  mask_t_kernel<<<(64 * 4096 + 255) / 256, 256, 0, stream>>>(mask, maskT);

  // x -> bf16
  convert_bf16_kernel<<<(131072 * 64 + 255) / 256, 256, 0, stream>>>(x, xb, 131072 * 64);

  // q/k GEMM (fused norm/scale, head-major) and V GEMM (transposed) — split kernels
  gemm_qk<<<8192, 256, 0, stream>>>(xb, wqkvT, qkv_ws, lscale, 131072, 512);
  gemm_v<<<4096, 256, 0, stream>>>(xb, wqkvT + (size_t)1024 * 512, qkv_ws, 131072, 512);

  // attention (reads qkv_ws, writes attn_out == xb)
  attn2<<<2048, 512, 0, stream>>>(qkv_ws, maskT, b16, attn_out);

  // out = attn_out @ w_out (fp32 stores)
  gemm_bt<true><<<4096, 256, 0, stream>>>(attn_out, woutT, out, 131072, 512, 512);
}

// Round 18
// 894.435 us; speedup vs baseline: 1.1295x; 1.0140x over previous
//
#include <hip/hip_runtime.h>
#include <hip/hip_bf16.h>

typedef unsigned short u16;
typedef unsigned int u32;
typedef __attribute__((ext_vector_type(8))) short bf16x8;
typedef __attribute__((ext_vector_type(4))) short bf16x4;
typedef __attribute__((ext_vector_type(4))) float f32x4;
typedef __attribute__((ext_vector_type(4))) float float4v;

__device__ __forceinline__ float bf2f(u16 v) {
  union { u32 u; float f; } x; x.u = ((u32)v) << 16; return x.f;
}
__device__ __forceinline__ u16 f2bf(float f) {
  union { u32 u; float f; } x; x.f = f;
  return (u16)((x.u + 0x7fffu + ((x.u >> 16) & 1u)) >> 16);
}

__device__ __forceinline__ void gload16(const void* g, void* l) {
  __builtin_amdgcn_global_load_lds(
      (const __attribute__((address_space(1))) u32*)g,
      (__attribute__((address_space(3))) u32*)l, 16, 0, 0);
}

#define MFMA16(a, bfr, cacc) __builtin_amdgcn_mfma_f32_16x16x32_bf16((a), (bfr), (cacc), 0, 0, 0)

// ---------------- prep kernels ----------------

__global__ void convert_bf16_kernel(const float* __restrict__ in,
                                    u16* __restrict__ out, int n8) {
  int t = blockIdx.x * blockDim.x + threadIdx.x;
  if (t >= n8) return;
  const float4v* p = (const float4v*)(in + (size_t)t * 8);
  float4v a = p[0], b = p[1];
  union { bf16x8 v; u16 s[8]; } o;
  o.s[0] = f2bf(a[0]); o.s[1] = f2bf(a[1]); o.s[2] = f2bf(a[2]); o.s[3] = f2bf(a[3]);
  o.s[4] = f2bf(b[0]); o.s[5] = f2bf(b[1]); o.s[6] = f2bf(b[2]); o.s[7] = f2bf(b[3]);
  *(bf16x8*)(out + (size_t)t * 8) = o.v;
}

__global__ void transpose_kernel(const float* __restrict__ in, u16* __restrict__ out,
                                 int R, int C) {
  int t = blockIdx.x * blockDim.x + threadIdx.x;
  if (t >= R * C) return;
  int c = t / R, r = t % R;
  out[t] = f2bf(in[r * C + c]);
}

// maskT[wm][m][n] = mask[wm][n][m]  (fp32, coalesced writes)
__global__ void mask_t_kernel(const float* __restrict__ in, float* __restrict__ out) {
  int t = blockIdx.x * blockDim.x + threadIdx.x;
  if (t >= 64 * 4096) return;
  int wm = t >> 12, rest = t & 4095, m = rest >> 6, n = rest & 63;
  out[t] = in[wm * 4096 + n * 64 + m];
}

__global__ void bias_tab_kernel(const float* __restrict__ w1, const float* __restrict__ w2,
                                float* __restrict__ tab) {
  int t = blockIdx.x * blockDim.x + threadIdx.x;
  if (t >= 225 * 16) return;
  int r = t >> 4, h = t & 15;
  int i = r / 15, j = r % 15;
  float gi = (float)(i - 7) * (8.0f / 7.0f);
  float gj = (float)(j - 7) * (8.0f / 7.0f);
  float si = (gi > 0.f) ? 1.f : ((gi < 0.f) ? -1.f : 0.f);
  float sj = (gj > 0.f) ? 1.f : ((gj < 0.f) ? -1.f : 0.f);
  float t0 = si * log2f(fabsf(gi) + 1.0f) * (1.0f / 3.0f);
  float t1 = sj * log2f(fabsf(gj) + 1.0f) * (1.0f / 3.0f);
  float acc = 0.f;
  for (int k = 0; k < 512; ++k) {
    float a = t0 * w1[k] + t1 * w1[512 + k];
    float hs = a * fminf(fmaxf(a + 3.f, 0.f), 6.f) * (1.f / 6.f);
    acc += hs * w2[k * 16 + h];
  }
  tab[t] = acc;
}

// bias16T[h][m][n] = 16*sigmoid(tab[idx(n,m)][h])   (TRANSPOSED for vector loads)
__global__ void bias16_kernel(const float* __restrict__ tab, float* __restrict__ b16) {
  int t = blockIdx.x * blockDim.x + threadIdx.x;
  if (t >= 16 * 64 * 64) return;
  int h = t >> 12, nm = t & 4095, m = nm >> 6, n = nm & 63;
  int idx = ((n >> 3) - (m >> 3) + 7) * 15 + ((n & 7) - (m & 7) + 7);
  float b = tab[idx * 16 + h];
  b16[t] = 16.0f / (1.0f + expf(-b));
}

// ---------------- m97-style bf16 GEMM (generic, swizzled): out-projection ----------
template <bool F32OUT>
__global__ __launch_bounds__(256) void gemm_bt(const u16* __restrict__ A,
                                               const u16* __restrict__ Bt,
                                               void* __restrict__ Cout,
                                               int M, int N, int K) {
  __shared__ u16 lA[128 * 64];
  __shared__ u16 lB[128 * 64];
  const int tid = threadIdx.x;
  const int w = tid >> 6, l = tid & 63;
  const int lg = l >> 4, li = l & 15;
  const int nbn = N >> 7;
  const int nwg = gridDim.x;
  int bidx = blockIdx.x;
  int q = nwg >> 3, r = nwg & 7;
  int xcd = bidx & 7, pos = bidx >> 3;
  int swz = (xcd < r ? xcd * (q + 1) : r * (q + 1) + (xcd - r) * q) + pos;
  int bm = swz / nbn, bn = swz % nbn;
  const int wr = w >> 1, wc = w & 1;

  f32x4 acc[4][4];
#pragma unroll
  for (int i = 0; i < 4; i++)
#pragma unroll
    for (int j = 0; j < 4; j++) acc[i][j] = (f32x4){0.f, 0.f, 0.f, 0.f};

  const u16* Abase = A + (size_t)(bm * 128) * K;
  const u16* Bbase = Bt + (size_t)(bn * 128) * K;

  for (int k0 = 0; k0 < K; k0 += 64) {
#pragma unroll
    for (int i = 0; i < 4; ++i) {
      int c = w * 256 + i * 64 + l;
      int row = c >> 3, kc = c & 7;
      int kcs = kc ^ (row & 7);
      gload16(Abase + (size_t)row * K + k0 + kcs * 8, (u16*)lA + c * 8);
      gload16(Bbase + (size_t)row * K + k0 + kcs * 8, (u16*)lB + c * 8);
    }
    __syncthreads();
#pragma unroll
    for (int kk = 0; kk < 2; ++kk) {
      bf16x8 af[4], bfr[4];
#pragma unroll
      for (int t = 0; t < 4; ++t) {
        int row = wr * 64 + t * 16 + li;
        af[t] = *(const bf16x8*)&lA[row * 64 + (((kk * 4 + lg) ^ (row & 7)) << 3)];
        int col = wc * 64 + t * 16 + li;
        bfr[t] = *(const bf16x8*)&lB[col * 64 + (((kk * 4 + lg) ^ (col & 7)) << 3)];
      }
#pragma unroll
      for (int tm = 0; tm < 4; ++tm)
#pragma unroll
        for (int tn = 0; tn < 4; ++tn)
          acc[tm][tn] = MFMA16(af[tm], bfr[tn], acc[tm][tn]);
    }
    __syncthreads();
  }
  int r0 = bm * 128 + wr * 64 + lg * 4;
  int c0 = bn * 128 + wc * 64 + li;
#pragma unroll
  for (int tm = 0; tm < 4; ++tm)
#pragma unroll
    for (int tn = 0; tn < 4; ++tn)
#pragma unroll
      for (int j = 0; j < 4; ++j) {
        size_t off = (size_t)(r0 + tm * 16 + j) * N + c0 + tn * 16;
        if (F32OUT)
          ((float*)Cout)[off] = acc[tm][tn][j];
        else
          ((u16*)Cout)[off] = f2bf(acc[tm][tn][j]);
      }
}

// ---------------- 128^2 q/k GEMM + fused cosine-norm + head-major store -----------
__global__ __launch_bounds__(256) void gemm_qk(const u16* __restrict__ A,
                                               const u16* __restrict__ Bt,
                                               u16* __restrict__ Cq,
                                               const float* __restrict__ lscale,
                                               int M, int K) {
  __shared__ u16 lds[128 * 136];
  u16* lA = lds;
  u16* lB = lds + 8192;
  const int tid = threadIdx.x;
  const int w = tid >> 6, l = tid & 63;
  const int lg = l >> 4, li = l & 15;
  const int nbn = 8;
  const int nwg = gridDim.x;
  int bidx = blockIdx.x;
  int q = nwg >> 3, r = nwg & 7;
  int xcd = bidx & 7, pos = bidx >> 3;
  int swz = (xcd < r ? xcd * (q + 1) : r * (q + 1) + (xcd - r) * q) + pos;
  int bm = swz / nbn, bn = swz % nbn;
  const int wr = w >> 1, wc = w & 1;

  f32x4 acc[4][4];
#pragma unroll
  for (int i = 0; i < 4; i++)
#pragma unroll
    for (int j = 0; j < 4; j++) acc[i][j] = (f32x4){0.f, 0.f, 0.f, 0.f};

  const u16* Abase = A + (size_t)(bm * 128) * K;
  const u16* Bbase = Bt + (size_t)(bn * 128) * K;

  for (int k0 = 0; k0 < K; k0 += 64) {
#pragma unroll
    for (int i = 0; i < 4; ++i) {
      int c = w * 256 + i * 64 + l;
      int row = c >> 3, kc = c & 7;
      int kcs = kc ^ (row & 7);  // source pre-swizzle (rule 21)
      gload16(Abase + (size_t)row * K + k0 + kcs * 8, lA + c * 8);
      gload16(Bbase + (size_t)row * K + k0 + kcs * 8, lB + c * 8);
    }
    __syncthreads();
#pragma unroll
    for (int kk = 0; kk < 2; ++kk) {
      bf16x8 af[4], bfr[4];
#pragma unroll
      for (int t = 0; t < 4; ++t) {
        int row = wr * 64 + t * 16 + li;
        af[t] = *(const bf16x8*)&lA[row * 64 + (((kk * 4 + lg) ^ (row & 7)) << 3)];
        int col = wc * 64 + t * 16 + li;
        bfr[t] = *(const bf16x8*)&lB[col * 64 + (((kk * 4 + lg) ^ (col & 7)) << 3)];
      }
#pragma unroll
      for (int tm = 0; tm < 4; ++tm)
#pragma unroll
        for (int tn = 0; tn < 4; ++tn)
          acc[tm][tn] = MFMA16(af[tm], bfr[tn], acc[tm][tn]);
    }
    __syncthreads();
  }

  const int s_t = bn >> 2;          // 0=q 1=k
  const int hq = (bn & 3) * 4;
  float scv[2];
  if (s_t == 0) {
    scv[0] = __expf(fminf(lscale[hq + wc * 2 + 0], 4.6051702f));
    scv[1] = __expf(fminf(lscale[hq + wc * 2 + 1], 4.6051702f));
  } else {
    scv[0] = scv[1] = 1.0f;
  }
#pragma unroll
  for (int tm = 0; tm < 4; ++tm)
#pragma unroll
    for (int g = 0; g < 2; ++g) {
      f32x4 s2;
#pragma unroll
      for (int j = 0; j < 4; ++j)
        s2[j] = acc[tm][2 * g][j] * acc[tm][2 * g][j] +
                acc[tm][2 * g + 1][j] * acc[tm][2 * g + 1][j];
#pragma unroll
      for (int m = 1; m <= 8; m <<= 1)
#pragma unroll
        for (int j = 0; j < 4; ++j) s2[j] += __shfl_xor(s2[j], m);
#pragma unroll
      for (int j = 0; j < 4; ++j) {
        float rn = scv[g] / fmaxf(sqrtf(s2[j]), 1e-12f);
        acc[tm][2 * g][j] *= rn;
        acc[tm][2 * g + 1][j] *= rn;
      }
    }
  u16* ct = lds;
#pragma unroll
  for (int tm = 0; tm < 4; ++tm)
#pragma unroll
    for (int tn = 0; tn < 4; ++tn)
#pragma unroll
      for (int j = 0; j < 4; ++j)
        ct[(wr * 64 + tm * 16 + lg * 4 + j) * 136 + wc * 64 + tn * 16 + li] =
            f2bf(acc[tm][tn][j]);
  __syncthreads();
  {
    int rr = tid >> 2;
    int c8 = (tid & 3) * 8;
#pragma unroll
    for (int bh = 0; bh < 2; ++bh)
#pragma unroll
      for (int ht = 0; ht < 4; ++ht) {
        bf16x8 v = *(const bf16x8*)(ct + (bh * 64 + rr) * 136 + ht * 32 + c8);
        size_t base = ((size_t)(s_t * 16 + hq + ht) * 2048 + (bm * 2 + bh)) * 2048;
        *(bf16x8*)(Cq + base + rr * 32 + c8) = v;
      }
  }
}

// ---------------- 128^2 V GEMM + transposed store [32+h][b][d][n] -----------------
__global__ __launch_bounds__(256) void gemm_v(const u16* __restrict__ A,
                                              const u16* __restrict__ Bt,
                                              u16* __restrict__ Cq,
                                              int M, int K) {
  __shared__ u16 lds[128 * 136];
  u16* lA = lds;
  u16* lB = lds + 8192;
  const int tid = threadIdx.x;
  const int w = tid >> 6, l = tid & 63;
  const int lg = l >> 4, li = l & 15;
  const int nbn = 4;
  const int nwg = gridDim.x;
  int bidx = blockIdx.x;
  int q = nwg >> 3, r = nwg & 7;
  int xcd = bidx & 7, pos = bidx >> 3;
  int swz = (xcd < r ? xcd * (q + 1) : r * (q + 1) + (xcd - r) * q) + pos;
  int bm = swz / nbn, bn = swz % nbn;
  const int wr = w >> 1, wc = w & 1;

  f32x4 acc[4][4];
#pragma unroll
  for (int i = 0; i < 4; i++)
#pragma unroll
    for (int j = 0; j < 4; j++) acc[i][j] = (f32x4){0.f, 0.f, 0.f, 0.f};

  const u16* Abase = A + (size_t)(bm * 128) * K;
  const u16* Bbase = Bt + (size_t)(bn * 128) * K;

  for (int k0 = 0; k0 < K; k0 += 64) {
#pragma unroll
    for (int i = 0; i < 4; ++i) {
      int c = w * 256 + i * 64 + l;
      int row = c >> 3, kc = c & 7;
      int kcs = kc ^ (row & 7);
      gload16(Abase + (size_t)row * K + k0 + kcs * 8, lA + c * 8);
      gload16(Bbase + (size_t)row * K + k0 + kcs * 8, lB + c * 8);
    }
    __syncthreads();
#pragma unroll
    for (int kk = 0; kk < 2; ++kk) {
      bf16x8 af[4], bfr[4];
#pragma unroll
      for (int t = 0; t < 4; ++t) {
        int row = wr * 64 + t * 16 + li;
        af[t] = *(const bf16x8*)&lA[row * 64 + (((kk * 4 + lg) ^ (row & 7)) << 3)];
        int col = wc * 64 + t * 16 + li;
        bfr[t] = *(const bf16x8*)&lB[col * 64 + (((kk * 4 + lg) ^ (col & 7)) << 3)];
      }
#pragma unroll
      for (int tm = 0; tm < 4; ++tm)
#pragma unroll
        for (int tn = 0; tn < 4; ++tn)
          acc[tm][tn] = MFMA16(af[tm], bfr[tn], acc[tm][tn]);
    }
    __syncthreads();
  }

  const int hq = bn * 4;
  u16* ctT = lds;
#pragma unroll
  for (int tm = 0; tm < 4; ++tm)
#pragma unroll
    for (int tn = 0; tn < 4; ++tn)
#pragma unroll
      for (int j = 0; j < 4; ++j)
        ctT[(wc * 64 + tn * 16 + li) * 136 + wr * 64 + tm * 16 + lg * 4 + j] =
            f2bf(acc[tm][tn][j]);
  __syncthreads();
#pragma unroll
  for (int r2 = 0; r2 < 8; ++r2) {
    int id = r2 * 256 + tid;
    int colc = id >> 4;
    int seg = id & 15;
    bf16x8 v = *(const bf16x8*)&ctT[colc * 136 + seg * 8];
    int ht = colc >> 5, d = colc & 31;
    int wi = seg >> 3, n0 = (seg & 7) * 8;
    size_t base = ((size_t)(32 + hq + ht) * 2048 + (bm * 2 + wi)) * 2048;
    *(bf16x8*)(Cq + base + d * 64 + n0) = v;
  }
}

// ---------------- attention-only: q,k head-major [h][b][n][d]; V^T [h][b][d][n] ----
// Two-phase softmax (vals in regs) + n-major compact P16r [16h][64n][20m] u16
// (aliases S after a barrier) -> PV P-frags via 2x ds_read_b64, conflict-free.
__global__ __launch_bounds__(512, 2) void attn2(const u16* __restrict__ qkv,
                                                const float* __restrict__ maskT,
                                                const float* __restrict__ bias16T,
                                                u16* __restrict__ aout) {
  __shared__ float S[16 * 1088];     // [h][m(16)][68-pad n] f32 = 69,632 B
  u16* P16r = (u16*)S;               // phase B alias: [16h][64n][20m] u16 = 40,960 B
  float* ob = S;                     // epilogue alias [16][516] f32
  const int tid = threadIdx.x;
  const int w = tid >> 6, l = tid & 63;
  const int lg = l >> 4, li = l & 15;
  const int b = blockIdx.x, wm = b & 63;
  const float* maskT_w = maskT + wm * 4096;

  // hoist Q fragments (loaded once, used in all 4 chunks)
  bf16x8 qfr[2][4];
#pragma unroll
  for (int hp = 0; hp < 2; ++hp) {
    const u16* qb = qkv + ((size_t)(w + hp * 8) * 2048 + b) * 2048;
#pragma unroll
    for (int tn = 0; tn < 4; ++tn)
      qfr[hp][tn] = *(const bf16x8*)(qb + (tn * 16 + li) * 32 + lg * 8);
  }

  f32x4 oacc[2][4][2];
#pragma unroll
  for (int hp = 0; hp < 2; ++hp)
#pragma unroll
    for (int i = 0; i < 4; ++i) {
      oacc[hp][i][0] = (f32x4){0.f, 0.f, 0.f, 0.f};
      oacc[hp][i][1] = (f32x4){0.f, 0.f, 0.f, 0.f};
    }

#pragma unroll
  for (int c = 0; c < 4; ++c) {
    // ---- QK^T chunk (16 keys) + bias + mask -> S (float4 loads, b128 writes) ----
#pragma unroll
    for (int hp = 0; hp < 2; ++hp) {
      int h = w + hp * 8;
      const u16* kb = qkv + ((size_t)(16 + h) * 2048 + b) * 2048;
      const float* biasT_h = bias16T + h * 4096;
      bf16x8 kfc = *(const bf16x8*)(kb + (c * 16 + li) * 32 + lg * 8);
      int mg = c * 16 + li;
#pragma unroll
      for (int tn = 0; tn < 4; ++tn) {
        f32x4 z = {0.f, 0.f, 0.f, 0.f};
        f32x4 s = MFMA16(qfr[hp][tn], kfc, z);
        float4v b4 = *(const float4v*)(biasT_h + mg * 64 + tn * 16 + lg * 4);
        float4v m4 = *(const float4v*)(maskT_w + mg * 64 + tn * 16 + lg * 4);
        *(float4v*)&S[h * 1088 + li * 68 + tn * 16 + lg * 4] = s + b4 + m4;
      }
    }
    __syncthreads();
    // ---- softmax phase A: read S into regs, exp + inv (no LDS writes yet) ----
    float vals[2][16];
    float inv[2];
#pragma unroll
    for (int pp = 0; pp < 2; ++pp) {
      int p = tid + pp * 512;
      int base = (p >> 6) * 68 + (p & 63);
      float mx = -3.0e38f;
#pragma unroll
      for (int hh = 0; hh < 16; ++hh) {
        vals[pp][hh] = S[hh * 1088 + base];
        mx = fmaxf(mx, vals[pp][hh]);
      }
      float sum = 0.f;
#pragma unroll
      for (int hh = 0; hh < 16; ++hh) {
        float e = __expf(vals[pp][hh] - mx);
        vals[pp][hh] = e;
        sum += e;
      }
      inv[pp] = 1.0f / sum;
    }
    __syncthreads();  // all S reads done; safe to overwrite with P16r
    // ---- softmax phase B: write compact n-major P16r[h][n][20m] ----
#pragma unroll
    for (int pp = 0; pp < 2; ++pp) {
      int p = tid + pp * 512;
      int m = p >> 6, n = p & 63;
#pragma unroll
      for (int hh = 0; hh < 16; ++hh)
        P16r[hh * 1280 + n * 20 + m] = f2bf(vals[pp][hh] * inv[pp]);
    }
    __syncthreads();
    // ---- PV (K=32 MFMA, upper 16 keys zero); P via b64, V^T via b128 ----
#pragma unroll
    for (int hp = 0; hp < 2; ++hp) {
      int h = w + hp * 8;
      const u16* vbT = qkv + ((size_t)(32 + h) * 2048 + b) * 2048;
      bf16x8 vf[2];
      if (lg < 2) {
#pragma unroll
        for (int td = 0; td < 2; ++td)
          vf[td] = *(const bf16x8*)(vbT + (td * 16 + li) * 64 + c * 16 + lg * 8);
      } else {
#pragma unroll
        for (int td = 0; td < 2; ++td)
#pragma unroll
          for (int e = 0; e < 8; ++e) vf[td][e] = 0;
      }
#pragma unroll
      for (int tn = 0; tn < 4; ++tn) {
        bf16x8 pf;
        if (lg < 2) {
          const u16* pb = P16r + h * 1280 + (tn * 16 + li) * 20 + lg * 8;
          bf16x4 plo = *(const bf16x4*)pb;
          bf16x4 phi = *(const bf16x4*)(pb + 4);
          pf[0] = plo[0]; pf[1] = plo[1]; pf[2] = plo[2]; pf[3] = plo[3];
          pf[4] = phi[0]; pf[5] = phi[1]; pf[6] = phi[2]; pf[7] = phi[3];
        } else {
#pragma unroll
          for (int e = 0; e < 8; ++e) pf[e] = 0;
        }
        oacc[hp][tn][0] = MFMA16(pf, vf[0], oacc[hp][tn][0]);
        oacc[hp][tn][1] = MFMA16(pf, vf[1], oacc[hp][tn][1]);
      }
    }
    __syncthreads();  // P16r reads done; next chunk overwrites S region
  }

  // ---- epilogue: 4 row-passes through ob, coalesced stores ----
#pragma unroll
  for (int tn = 0; tn < 4; ++tn) {
#pragma unroll
    for (int hp = 0; hp < 2; ++hp) {
      int h = w + hp * 8;
#pragma unroll
      for (int td = 0; td < 2; ++td)
#pragma unroll
        for (int j = 0; j < 4; ++j)
          ob[(lg * 4 + j) * 516 + h * 32 + td * 16 + li] = oacc[hp][tn][td][j];
    }
    __syncthreads();
    {
      int rr = tid >> 5, c16 = (tid & 31) * 16;
      const float* src = ob + rr * 516 + c16;
      u16* dst = aout + ((size_t)b * 64 + tn * 16 + rr) * 512 + c16;
#pragma unroll
      for (int half = 0; half < 2; ++half) {
        union { bf16x8 v; u16 u[8]; } o;
#pragma unroll
        for (int e = 0; e < 8; ++e) o.u[e] = f2bf(src[half * 8 + e]);
        *(bf16x8*)(dst + half * 8) = o.v;
      }
    }
    __syncthreads();
  }
}

extern "C" void kernel_launch(void* const* d_in, const int* in_sizes, int n_in,
                              void* d_out, int out_size, void* d_ws, size_t ws_size,
                              hipStream_t stream) {
  const float* x = (const float*)d_in[0];
  const float* mask = (const float*)d_in[1];
  const float* w_qkv = (const float*)d_in[2];
  const float* w_out = (const float*)d_in[3];
  const float* cpb_w1 = (const float*)d_in[4];
  const float* cpb_w2 = (const float*)d_in[5];
  const float* lscale = (const float*)d_in[6];
  float* out = (float*)d_out;

  char* ws = (char*)d_ws;
  u16* wqkvT = (u16*)ws;                          // 1,572,864 B
  u16* woutT = (u16*)(ws + 1572864ull);           // 524,288 B
  float* btab = (float*)(ws + 2097152ull);        // 16,384 B
  float* b16 = (float*)(ws + 2113536ull);         // 262,144 B (transposed [h][m][n])
  float* maskT = (float*)(ws + 2375680ull);       // 16,777,216 B ([w][m][n])
  u16* qkv_ws = (u16*)(ws + 19152896ull);         // 402,653,184 B (head-major / V^T)
  u16* xb = (u16*)(ws + 19152896ull + 402653184ull);  // 134,217,728 B
  u16* attn_out = xb;  // alias: xb dead after gemm_qk/gemm_v; attn2 runs after

  // prep
  transpose_kernel<<<(512 * 1536 + 255) / 256, 256, 0, stream>>>(w_qkv, wqkvT, 512, 1536);
  transpose_kernel<<<(512 * 512 + 255) / 256, 256, 0, stream>>>(w_out, woutT, 512, 512);
  bias_tab_kernel<<<(225 * 16 + 255) / 256, 256, 0, stream>>>(cpb_w1, cpb_w2, btab);
  bias16_kernel<<<(16 * 64 * 64 + 255) / 256, 256, 0, stream>>>(btab, b16);
  mask_t_kernel<<<(64 * 4096 + 255) / 256, 256, 0, stream>>>(mask, maskT);

  // x -> bf16
  convert_bf16_kernel<<<(131072 * 64 + 255) / 256, 256, 0, stream>>>(x, xb, 131072 * 64);

  // q/k GEMM (fused norm/scale, head-major) and V GEMM (transposed) — split kernels
  gemm_qk<<<8192, 256, 0, stream>>>(xb, wqkvT, qkv_ws, lscale, 131072, 512);
  gemm_v<<<4096, 256, 0, stream>>>(xb, wqkvT + (size_t)1024 * 512, qkv_ws, 131072, 512);

  // attention (reads qkv_ws, writes attn_out == xb)
  attn2<<<2048, 512, 0, stream>>>(qkv_ws, maskT, b16, attn_out);

  // out = attn_out @ w_out (fp32 stores)
  gemm_bt<true><<<4096, 256, 0, stream>>>(attn_out, woutT, out, 131072, 512, 512);
}